// Round 13
// baseline (717.393 us; speedup 1.0000x reference)
//
#include <hip/hip_runtime.h>
#include <stdint.h>

using f32x4  = __attribute__((ext_vector_type(4))) float;
using f32x16 = __attribute__((ext_vector_type(16))) float;
using bf16x8 = __attribute__((ext_vector_type(8))) short;

#define DEV static __device__ __forceinline__

DEV unsigned short f2bf(float f){
  union { float f; unsigned int u; } c; c.f = f;
  unsigned int u = c.u;
  u += 0x7FFFu + ((u >> 16) & 1u);   // round-to-nearest-even
  return (unsigned short)(u >> 16);
}
DEV float bf2f(unsigned short u){
  union { unsigned int u; float f; } c; c.u = ((unsigned int)u) << 16; return c.f;
}

DEV void gld_lds16(const void* g, void* l){
  __builtin_amdgcn_global_load_lds(
      (const __attribute__((address_space(1))) void*)g,
      (__attribute__((address_space(3))) void*)l, 16, 0, 0);
}

DEV void nt_store4(float* p, float a, float b, float c, float d){
  f32x4 v; v[0]=a; v[1]=b; v[2]=c; v[3]=d;
  __builtin_nontemporal_store(v, (f32x4*)p);
}

// ---------------------------------------------------------------- converts
__global__ __launch_bounds__(256) void cvt_f32_bf16(
    const float* __restrict__ in, unsigned short* __restrict__ out, int n){
  for (int i = (blockIdx.x*256 + threadIdx.x)*4; i < n; i += gridDim.x*1024){
    float4 v = *(const float4*)(in + i);
    ushort4 o; o.x=f2bf(v.x); o.y=f2bf(v.y); o.z=f2bf(v.z); o.w=f2bf(v.w);
    *(ushort4*)(out + i) = o;
  }
}

// ---------------------------------------------------------------- GEMM v2
// (byte-identical to round 10 — proven winner, untouched)
template<bool OUT_BF16, bool RELU, bool HAS_BIAS>
__global__ __launch_bounds__(512, 2)
void gemm_bt2(const unsigned short* __restrict__ Ap, const unsigned short* __restrict__ Bp,
              const float* __restrict__ bias, void* __restrict__ Cp, int N, int K)
{
  __shared__ __align__(16) char lds[131072];  // A: 3x32K @0 | B: 2x16K @98304
  const int tid  = threadIdx.x;
  const int lane = tid & 63;
  const int wid  = tid >> 6;          // 0..7
  const int wm   = wid >> 2;          // 0,1
  const int wn   = wid & 3;           // 0..3
  const int mrow = lane & 15;
  const int krow = lane >> 4;

  const int nbx = N >> 7;
  const int nwg = gridDim.x;
  const int d   = blockIdx.x;
  const int swz = (d & 7)*(nwg >> 3) + (d >> 3);
  const int bx  = swz % nbx, by = swz / nbx;

  const size_t Kb = (size_t)K * 2;
  const char* Ab = (const char*)(Ap + (size_t)by*256*K);
  const char* Bb = (const char*)(Bp + (size_t)bx*128*K);
  const int NT = K >> 6;

  auto stageA = [&](int t){
    char* dst = lds + (t % 3)*32768;
    const char* src = Ab + (size_t)t*128;
    #pragma unroll
    for (int s = 0; s < 4; ++s){
      int o = s*8192 + tid*16;
      int row = o >> 7, cb = o & 127;
      gld_lds16(src + (size_t)row*Kb + (cb ^ ((row & 7) << 4)), dst + o);
    }
  };
  auto stageB = [&](int t){
    char* dst = lds + 98304 + (t & 1)*16384;
    const char* src = Bb + (size_t)t*128;
    #pragma unroll
    for (int s = 0; s < 2; ++s){
      int o = s*8192 + tid*16;
      int row = o >> 7, cb = o & 127;
      gld_lds16(src + (size_t)row*Kb + (cb ^ ((row & 7) << 4)), dst + o);
    }
  };

  f32x4 acc[8][2] = {};

  stageA(0); stageB(0); stageA(1);
  asm volatile("s_waitcnt vmcnt(4)" ::: "memory");
  __builtin_amdgcn_s_barrier();

  for (int t = 0; t < NT; ++t){
    if (t + 1 < NT) stageB(t + 1);
    if (t + 2 < NT) stageA(t + 2);

    const char* baseA = lds + (t % 3)*32768;
    const char* baseB = lds + 98304 + (t & 1)*16384;

    bf16x8 b[2][2];
    #pragma unroll
    for (int ni = 0; ni < 2; ++ni){
      int row = wn*32 + ni*16 + mrow;
      #pragma unroll
      for (int ks = 0; ks < 2; ++ks)
        b[ni][ks] = *(const bf16x8*)(baseB + row*128 + ((ks*64 + krow*16) ^ ((row & 7) << 4)));
    }
    bf16x8 a[8][2];
    #pragma unroll
    for (int mi = 0; mi < 8; ++mi){
      int row = wm*128 + mi*16 + mrow;
      #pragma unroll
      for (int ks = 0; ks < 2; ++ks)
        a[mi][ks] = *(const bf16x8*)(baseA + row*128 + ((ks*64 + krow*16) ^ ((row & 7) << 4)));
    }

    __builtin_amdgcn_s_setprio(1);
    #pragma unroll
    for (int ks = 0; ks < 2; ++ks)
      #pragma unroll
      for (int mi = 0; mi < 8; ++mi)
        #pragma unroll
        for (int ni = 0; ni < 2; ++ni)
          acc[mi][ni] = __builtin_amdgcn_mfma_f32_16x16x32_bf16(a[mi][ks], b[ni][ks], acc[mi][ni], 0, 0, 0);
    __builtin_amdgcn_s_setprio(0);

    if (t + 1 < NT){
      if (t + 2 < NT) asm volatile("s_waitcnt vmcnt(4)" ::: "memory");
      else            asm volatile("s_waitcnt vmcnt(0)" ::: "memory");
      __builtin_amdgcn_s_barrier();
      __builtin_amdgcn_sched_barrier(0);
    }
  }

  int row0 = by*256 + wm*128;
  int col0 = bx*128 + wn*32;
  #pragma unroll
  for (int mi = 0; mi < 8; ++mi){
    #pragma unroll
    for (int ni = 0; ni < 2; ++ni){
      int col = col0 + ni*16 + mrow;
      float bv = HAS_BIAS ? bias[col] : 0.f;
      #pragma unroll
      for (int r = 0; r < 4; ++r){
        int row = row0 + mi*16 + krow*4 + r;
        float v = acc[mi][ni][r] + bv;
        if (RELU) v = fmaxf(v, 0.f);
        if (OUT_BF16) ((unsigned short*)Cp)[(size_t)row*N + col] = f2bf(v);
        else          ((float*)Cp)[(size_t)row*N + col] = v;
      }
    }
  }
}

// ---------------------------------------------------------------- V transpose
__global__ __launch_bounds__(256) void transpose_v(
    const unsigned short* __restrict__ V, unsigned short* __restrict__ Vt){
  __shared__ unsigned short t[32][33];
  int g = blockIdx.z;
  int j0 = blockIdx.x*32, e0 = blockIdx.y*32;
  int tx = threadIdx.x, ty = threadIdx.y;      // 32 x 8
  const unsigned short* Vg = V + (long)g*262144;
  unsigned short* Vtg = Vt + (long)g*262144;
  #pragma unroll
  for (int i = 0; i < 4; ++i)
    t[ty + 8*i][tx] = Vg[(long)(j0 + ty + 8*i)*128 + e0 + tx];
  __syncthreads();
  #pragma unroll
  for (int i = 0; i < 4; ++i)
    Vtg[(long)(e0 + ty + 8*i)*2048 + j0 + tx] = t[tx][ty + 8*i];
}

// ---------------------------------------------------------------- fused attention
// R10 body (proven ~228us) with ONE change: P stores are NON-TEMPORAL so the
// 537MB streaming write bypasses L2 and stops evicting the K/Vt working set
// (4 groups x 1MB per XCD must stay L2-resident for the staging reads).
__global__ __launch_bounds__(256, 2) void attn_fused(
    const unsigned short* __restrict__ Q, const unsigned short* __restrict__ K,
    const unsigned short* __restrict__ Vt, float* __restrict__ P,
    unsigned short* __restrict__ CTX)
{
  __shared__ __align__(16) char lds[65536];   // K dbuf 2x16K | Vt dbuf 2x16K
  char* ldsK = lds;
  char* ldsV = lds + 32768;
  const int tid  = threadIdx.x;       // 0..255
  const int lane = tid & 63;
  const int w    = tid >> 6;          // 0..3
  const int l31  = lane & 31;
  const int hi   = lane >> 5;         // 0,1
  const float scale = 0.08838834764831845f;    // 128^-0.5

  const int d  = blockIdx.x;          // 0..511
  const int i  = d >> 3;              // 0..63
  const int g  = (d & 7) + 8*(i >> 4);
  const int q0 = (i & 15) * 128;

  const char* KbB = (const char*)(K  + (size_t)g*262144);
  const char* VtB = (const char*)(Vt + (size_t)g*262144);
  const unsigned short* Qb = Q + (size_t)g*262144 + (size_t)(q0 + w*32)*128;
  float* Pb = P + (size_t)g*4194304 + (size_t)(q0 + w*32)*2048;

  bf16x8 qf[8];
  #pragma unroll
  for (int kk = 0; kk < 8; ++kk)
    qf[kk] = *(const bf16x8*)((const char*)Qb + (size_t)l31*256 + kk*32 + hi*16);

  auto stageK = [&](int buf, int j0b){
    #pragma unroll
    for (int r = 0; r < 4; ++r){
      int o = r*4096 + tid*16;
      int j = o >> 8, c = o & 255;
      gld_lds16(KbB + (size_t)(j0b + j)*256 + (c ^ ((j & 15) << 4)),
                ldsK + buf*16384 + o);
    }
  };
  auto stageV = [&](int buf, int j0b){
    #pragma unroll
    for (int r = 0; r < 4; ++r){
      int o = r*4096 + tid*16;
      int e = o >> 7, c = o & 127;
      gld_lds16(VtB + (size_t)e*4096 + j0b*2 + (c ^ ((e & 7) << 4)),
                ldsV + buf*16384 + o);
    }
  };
  auto readK = [&](int buf, int jloc, int kk) -> bf16x8 {
    int row = jloc + l31;
    int col = (kk*32 + hi*16) ^ ((l31 & 15) << 4);
    return *(const bf16x8*)(ldsK + buf*16384 + row*256 + col);
  };
  auto readV = [&](int buf, int jloc, int c16, int t) -> bf16x8 {
    int row = t*32 + l31;
    int col = (jloc*2 + c16*32 + hi*16) ^ ((row & 7) << 4);
    return *(const bf16x8*)(ldsV + buf*16384 + row*128 + col);
  };

  // ---------------- pass 1 ----------------
  int buf = 0;
  stageK(0, 0);
  __syncthreads();
  float lacc = 0.f;
  for (int st = 0; st < 32; ++st){
    if (st < 31) stageK(buf ^ 1, (st + 1) * 64);
    #pragma unroll
    for (int jt = 0; jt < 2; ++jt){
      const int jloc = jt * 32;
      f32x16 s1 = {}, s2 = {};
      #pragma unroll
      for (int kk = 0; kk < 4; ++kk){
        s1 = __builtin_amdgcn_mfma_f32_32x32x16_bf16(readK(buf, jloc, kk),   qf[kk],   s1, 0, 0, 0);
        s2 = __builtin_amdgcn_mfma_f32_32x32x16_bf16(readK(buf, jloc, kk+4), qf[kk+4], s2, 0, 0, 0);
      }
      #pragma unroll
      for (int r = 0; r < 16; ++r) lacc += __expf((s1[r] + s2[r]) * scale);
    }
    __syncthreads();
    buf ^= 1;
  }
  lacc += __shfl_xor(lacc, 32, 64);
  const float invl = 1.f / lacc;

  // ---------------- pass 2 ----------------
  stageK(0, 0); stageV(0, 0);
  __syncthreads();
  f32x16 O[4] = {};
  buf = 0;
  for (int st = 0; st < 32; ++st){
    if (st < 31){ stageK(buf ^ 1, (st + 1) * 64); stageV(buf ^ 1, (st + 1) * 64); }
    #pragma unroll
    for (int jt = 0; jt < 2; ++jt){
      const int jloc  = jt * 32;
      const int jglob = st*64 + jloc;
      f32x16 s1 = {}, s2 = {};
      #pragma unroll
      for (int kk = 0; kk < 4; ++kk){
        s1 = __builtin_amdgcn_mfma_f32_32x32x16_bf16(readK(buf, jloc, kk),   qf[kk],   s1, 0, 0, 0);
        s2 = __builtin_amdgcn_mfma_f32_32x32x16_bf16(readK(buf, jloc, kk+4), qf[kk+4], s2, 0, 0, 0);
      }
      float p[16];
      #pragma unroll
      for (int r = 0; r < 16; ++r) p[r] = __expf((s1[r] + s2[r]) * scale) * invl;
      // exact fp32 P -> d_out, NON-TEMPORAL (bypass L2; never re-read on GPU)
      float* prow = Pb + (size_t)l31*2048 + jglob + hi*4;
      nt_store4(prow,      p[0],  p[1],  p[2],  p[3]);
      nt_store4(prow + 8,  p[4],  p[5],  p[6],  p[7]);
      nt_store4(prow + 16, p[8],  p[9],  p[10], p[11]);
      nt_store4(prow + 24, p[12], p[13], p[14], p[15]);
      unsigned int pk[8];
      #pragma unroll
      for (int ii = 0; ii < 8; ++ii)
        pk[ii] = (unsigned int)f2bf(p[2*ii]) | ((unsigned int)f2bf(p[2*ii+1]) << 16);
      unsigned int r0 = (unsigned int)__shfl_xor((int)(hi ? pk[0] : pk[2]), 32, 64);
      unsigned int r1 = (unsigned int)__shfl_xor((int)(hi ? pk[1] : pk[3]), 32, 64);
      unsigned int r2 = (unsigned int)__shfl_xor((int)(hi ? pk[4] : pk[6]), 32, 64);
      unsigned int r3 = (unsigned int)__shfl_xor((int)(hi ? pk[5] : pk[7]), 32, 64);
      union U { unsigned int u[4]; bf16x8 v; };
      U a0, a1;
      a0.u[0] = hi ? r0    : pk[0];  a0.u[1] = hi ? r1    : pk[1];
      a0.u[2] = hi ? pk[2] : r0;     a0.u[3] = hi ? pk[3] : r1;
      a1.u[0] = hi ? r2    : pk[4];  a1.u[1] = hi ? r3    : pk[5];
      a1.u[2] = hi ? pk[6] : r2;     a1.u[3] = hi ? pk[7] : r3;
      #pragma unroll
      for (int t = 0; t < 4; ++t){
        O[t] = __builtin_amdgcn_mfma_f32_32x32x16_bf16(a0.v, readV(buf, jloc, 0, t), O[t], 0, 0, 0);
        O[t] = __builtin_amdgcn_mfma_f32_32x32x16_bf16(a1.v, readV(buf, jloc, 1, t), O[t], 0, 0, 0);
      }
    }
    __syncthreads();
    buf ^= 1;
  }

  #pragma unroll
  for (int t = 0; t < 4; ++t){
    #pragma unroll
    for (int r = 0; r < 16; ++r){
      int qrow = (r & 3) + 8*(r >> 2) + 4*hi;
      CTX[(size_t)g*262144 + (size_t)(q0 + w*32 + qrow)*128 + t*32 + l31] = f2bf(O[t][r]);
    }
  }
}

// ---------------------------------------------------------------- LayerNorm
DEV float block_sum256(float v, float* red){
  #pragma unroll
  for (int off = 32; off > 0; off >>= 1) v += __shfl_xor(v, off, 64);
  int lane = threadIdx.x & 63, wid = threadIdx.x >> 6;
  if (lane == 0) red[wid] = v;
  __syncthreads();
  return (red[0]+red[1]) + (red[2]+red[3]);
}

template<bool WRITE_F32, bool WRITE_BF>
__global__ __launch_bounds__(256) void ln_residual_bf(
    const unsigned short* __restrict__ A, const unsigned short* __restrict__ R,
    const float* __restrict__ gamma, const float* __restrict__ beta,
    float* __restrict__ outf, unsigned short* __restrict__ outb){
  __shared__ float red1[4], red2[4];
  long base = (long)blockIdx.x * 1024;
  int tid = threadIdx.x;
  ushort4 a = *(const ushort4*)(A + base + tid*4);
  ushort4 r = *(const ushort4*)(R + base + tid*4);
  float v[4] = { bf2f(a.x)+bf2f(r.x), bf2f(a.y)+bf2f(r.y),
                 bf2f(a.z)+bf2f(r.z), bf2f(a.w)+bf2f(r.w) };
  float s = (v[0]+v[1]) + (v[2]+v[3]);
  s = block_sum256(s, red1);
  float mean = s * (1.f/1024.f);
  float dd[4] = {v[0]-mean, v[1]-mean, v[2]-mean, v[3]-mean};
  float sq = (dd[0]*dd[0]+dd[1]*dd[1]) + (dd[2]*dd[2]+dd[3]*dd[3]);
  sq = block_sum256(sq, red2);
  float rstd = rsqrtf(sq*(1.f/1024.f) + 1e-5f);
  float4 g4 = *(const float4*)(gamma + tid*4);
  float4 b4 = *(const float4*)(beta  + tid*4);
  float o[4] = { dd[0]*rstd*g4.x + b4.x, dd[1]*rstd*g4.y + b4.y,
                 dd[2]*rstd*g4.z + b4.z, dd[3]*rstd*g4.w + b4.w };
  if (WRITE_F32){
    // y output: never re-read on GPU -> non-temporal
    nt_store4(outf + base + tid*4, o[0], o[1], o[2], o[3]);
  }
  if (WRITE_BF){
    ushort4 ob; ob.x=f2bf(o[0]); ob.y=f2bf(o[1]); ob.z=f2bf(o[2]); ob.w=f2bf(o[3]);
    *(ushort4*)(outb + base + tid*4) = ob;
  }
}

// ---------------------------------------------------------------- host
extern "C" void kernel_launch(void* const* d_in, const int* in_sizes, int n_in,
                              void* d_out, int out_size, void* d_ws, size_t ws_size,
                              hipStream_t stream){
  const float* X   = (const float*)d_in[0];
  const float* Wq  = (const float*)d_in[1];
  const float* bq  = (const float*)d_in[2];
  const float* Wk  = (const float*)d_in[3];
  const float* bk  = (const float*)d_in[4];
  const float* Wv  = (const float*)d_in[5];
  const float* bv  = (const float*)d_in[6];
  const float* Wo  = (const float*)d_in[7];
  const float* bo  = (const float*)d_in[8];
  const float* g1  = (const float*)d_in[9];
  const float* b1n = (const float*)d_in[10];
  const float* W1  = (const float*)d_in[11];
  const float* b1  = (const float*)d_in[12];
  const float* W2  = (const float*)d_in[13];
  const float* b2  = (const float*)d_in[14];
  const float* g2  = (const float*)d_in[15];
  const float* b2n = (const float*)d_in[16];

  const int M = 8192, D = 1024, F = 2048;
  const long YSZ = (long)M * D;
  float* y_out = (float*)d_out;
  float* atten = (float*)d_out + YSZ;        // 32 x 2048 x 2048 fp32

  char* w = (char*)d_ws;
  auto alloc = [&](size_t bytes){ char* p = w; w += (bytes + 255) & ~(size_t)255; return p; };
  unsigned short* Xbf   = (unsigned short*)alloc((size_t)M*D*2);
  unsigned short* Wqbf  = (unsigned short*)alloc((size_t)D*D*2);
  unsigned short* Wkbf  = (unsigned short*)alloc((size_t)D*D*2);
  unsigned short* Wvbf  = (unsigned short*)alloc((size_t)D*D*2);
  unsigned short* Wobf  = (unsigned short*)alloc((size_t)D*D*2);
  unsigned short* W1bf  = (unsigned short*)alloc((size_t)F*D*2);
  unsigned short* W2bf  = (unsigned short*)alloc((size_t)D*F*2);
  unsigned short* Qbf   = (unsigned short*)alloc((size_t)M*D*2);
  unsigned short* Kbf   = (unsigned short*)alloc((size_t)M*D*2);
  unsigned short* Vbf   = (unsigned short*)alloc((size_t)M*D*2);
  unsigned short* Vtbf  = (unsigned short*)alloc((size_t)M*D*2);
  unsigned short* CTXbf = (unsigned short*)alloc((size_t)M*D*2);
  unsigned short* Hbf   = (unsigned short*)alloc((size_t)M*D*2);
  unsigned short* F1bf  = (unsigned short*)alloc((size_t)M*F*2);
  unsigned short* TMPbf = (unsigned short*)alloc((size_t)M*D*2);

  auto cvt = [&](const float* src, unsigned short* dst, int n){
    int blocks = (n/4 + 255)/256; if (blocks > 4096) blocks = 4096;
    cvt_f32_bf16<<<blocks, 256, 0, stream>>>(src, dst, n);
  };
  cvt(X,  Xbf,  M*D);
  cvt(Wq, Wqbf, D*D);  cvt(Wk, Wkbf, D*D);  cvt(Wv, Wvbf, D*D);  cvt(Wo, Wobf, D*D);
  cvt(W1, W1bf, F*D);  cvt(W2, W2bf, D*F);

  dim3 blk2(512);

  // Q/K/V projections: [8192,1024] = X @ W^T + b  -> bf16
  gemm_bt2<true,false,true><<<dim3((M/256)*(D/128)), blk2, 0, stream>>>(Xbf, Wqbf, bq, Qbf, D, D);
  gemm_bt2<true,false,true><<<dim3((M/256)*(D/128)), blk2, 0, stream>>>(Xbf, Wkbf, bk, Kbf, D, D);
  gemm_bt2<true,false,true><<<dim3((M/256)*(D/128)), blk2, 0, stream>>>(Xbf, Wvbf, bv, Vbf, D, D);

  // V -> Vt per group (e-major rows for PV B-operand staging)
  transpose_v<<<dim3(64, 4, 32), dim3(32, 8), 0, stream>>>(Vbf, Vtbf);

  // fused attention (R10 body + non-temporal P stores); 2 blocks/CU
  attn_fused<<<dim3(512), dim3(256), 0, stream>>>(Qbf, Kbf, Vtbf, atten, CTXbf);

  // out = ctx @ Wo^T + bo -> TMPbf (bf16)
  gemm_bt2<true,false,true><<<dim3((M/256)*(D/128)), blk2, 0, stream>>>(CTXbf, Wobf, bo, TMPbf, D, D);

  // h = LN1(X + out) -> Hbf (bf16 only)
  ln_residual_bf<false,true><<<M, 256, 0, stream>>>(Xbf, TMPbf, g1, b1n, nullptr, Hbf);

  // f1 = relu(h @ W1^T + b1) -> bf16
  gemm_bt2<true,true,true><<<dim3((M/256)*(F/128)), blk2, 0, stream>>>(Hbf, W1bf, b1, F1bf, F, D);

  // f = f1 @ W2^T + b2 -> TMPbf (bf16)
  gemm_bt2<true,false,true><<<dim3((M/256)*(D/128)), blk2, 0, stream>>>(F1bf, W2bf, b2, TMPbf, D, F);

  // y = LN2(h + f) -> d_out
  ln_residual_bf<true,false><<<M, 256, 0, stream>>>(Hbf, TMPbf, g2, b2n, y_out, nullptr);
}

// Round 14
// 479.703 us; speedup vs baseline: 1.4955x; 1.4955x over previous
//
#include <hip/hip_runtime.h>
#include <stdint.h>

using f32x4  = __attribute__((ext_vector_type(4))) float;
using f32x16 = __attribute__((ext_vector_type(16))) float;
using bf16x8 = __attribute__((ext_vector_type(8))) short;

#define DEV static __device__ __forceinline__

DEV unsigned short f2bf(float f){
  union { float f; unsigned int u; } c; c.f = f;
  unsigned int u = c.u;
  u += 0x7FFFu + ((u >> 16) & 1u);   // round-to-nearest-even
  return (unsigned short)(u >> 16);
}
DEV float bf2f(unsigned short u){
  union { unsigned int u; float f; } c; c.u = ((unsigned int)u) << 16; return c.f;
}

DEV void gld_lds16(const void* g, void* l){
  __builtin_amdgcn_global_load_lds(
      (const __attribute__((address_space(1))) void*)g,
      (__attribute__((address_space(3))) void*)l, 16, 0, 0);
}

// ---------------------------------------------------------------- converts
__global__ __launch_bounds__(256) void cvt_f32_bf16(
    const float* __restrict__ in, unsigned short* __restrict__ out, int n){
  for (int i = (blockIdx.x*256 + threadIdx.x)*4; i < n; i += gridDim.x*1024){
    float4 v = *(const float4*)(in + i);
    ushort4 o; o.x=f2bf(v.x); o.y=f2bf(v.y); o.z=f2bf(v.z); o.w=f2bf(v.w);
    *(ushort4*)(out + i) = o;
  }
}

// ---------------------------------------------------------------- GEMM v2
// (byte-identical to round 10 — proven winner, untouched)
template<bool OUT_BF16, bool RELU, bool HAS_BIAS>
__global__ __launch_bounds__(512, 2)
void gemm_bt2(const unsigned short* __restrict__ Ap, const unsigned short* __restrict__ Bp,
              const float* __restrict__ bias, void* __restrict__ Cp, int N, int K)
{
  __shared__ __align__(16) char lds[131072];  // A: 3x32K @0 | B: 2x16K @98304
  const int tid  = threadIdx.x;
  const int lane = tid & 63;
  const int wid  = tid >> 6;          // 0..7
  const int wm   = wid >> 2;          // 0,1
  const int wn   = wid & 3;           // 0..3
  const int mrow = lane & 15;
  const int krow = lane >> 4;

  const int nbx = N >> 7;
  const int nwg = gridDim.x;
  const int d   = blockIdx.x;
  const int swz = (d & 7)*(nwg >> 3) + (d >> 3);
  const int bx  = swz % nbx, by = swz / nbx;

  const size_t Kb = (size_t)K * 2;
  const char* Ab = (const char*)(Ap + (size_t)by*256*K);
  const char* Bb = (const char*)(Bp + (size_t)bx*128*K);
  const int NT = K >> 6;

  auto stageA = [&](int t){
    char* dst = lds + (t % 3)*32768;
    const char* src = Ab + (size_t)t*128;
    #pragma unroll
    for (int s = 0; s < 4; ++s){
      int o = s*8192 + tid*16;
      int row = o >> 7, cb = o & 127;
      gld_lds16(src + (size_t)row*Kb + (cb ^ ((row & 7) << 4)), dst + o);
    }
  };
  auto stageB = [&](int t){
    char* dst = lds + 98304 + (t & 1)*16384;
    const char* src = Bb + (size_t)t*128;
    #pragma unroll
    for (int s = 0; s < 2; ++s){
      int o = s*8192 + tid*16;
      int row = o >> 7, cb = o & 127;
      gld_lds16(src + (size_t)row*Kb + (cb ^ ((row & 7) << 4)), dst + o);
    }
  };

  f32x4 acc[8][2] = {};

  stageA(0); stageB(0); stageA(1);
  asm volatile("s_waitcnt vmcnt(4)" ::: "memory");
  __builtin_amdgcn_s_barrier();

  for (int t = 0; t < NT; ++t){
    if (t + 1 < NT) stageB(t + 1);
    if (t + 2 < NT) stageA(t + 2);

    const char* baseA = lds + (t % 3)*32768;
    const char* baseB = lds + 98304 + (t & 1)*16384;

    bf16x8 b[2][2];
    #pragma unroll
    for (int ni = 0; ni < 2; ++ni){
      int row = wn*32 + ni*16 + mrow;
      #pragma unroll
      for (int ks = 0; ks < 2; ++ks)
        b[ni][ks] = *(const bf16x8*)(baseB + row*128 + ((ks*64 + krow*16) ^ ((row & 7) << 4)));
    }
    bf16x8 a[8][2];
    #pragma unroll
    for (int mi = 0; mi < 8; ++mi){
      int row = wm*128 + mi*16 + mrow;
      #pragma unroll
      for (int ks = 0; ks < 2; ++ks)
        a[mi][ks] = *(const bf16x8*)(baseA + row*128 + ((ks*64 + krow*16) ^ ((row & 7) << 4)));
    }

    __builtin_amdgcn_s_setprio(1);
    #pragma unroll
    for (int ks = 0; ks < 2; ++ks)
      #pragma unroll
      for (int mi = 0; mi < 8; ++mi)
        #pragma unroll
        for (int ni = 0; ni < 2; ++ni)
          acc[mi][ni] = __builtin_amdgcn_mfma_f32_16x16x32_bf16(a[mi][ks], b[ni][ks], acc[mi][ni], 0, 0, 0);
    __builtin_amdgcn_s_setprio(0);

    if (t + 1 < NT){
      if (t + 2 < NT) asm volatile("s_waitcnt vmcnt(4)" ::: "memory");
      else            asm volatile("s_waitcnt vmcnt(0)" ::: "memory");
      __builtin_amdgcn_s_barrier();
      __builtin_amdgcn_sched_barrier(0);
    }
  }

  int row0 = by*256 + wm*128;
  int col0 = bx*128 + wn*32;
  #pragma unroll
  for (int mi = 0; mi < 8; ++mi){
    #pragma unroll
    for (int ni = 0; ni < 2; ++ni){
      int col = col0 + ni*16 + mrow;
      float bv = HAS_BIAS ? bias[col] : 0.f;
      #pragma unroll
      for (int r = 0; r < 4; ++r){
        int row = row0 + mi*16 + krow*4 + r;
        float v = acc[mi][ni][r] + bv;
        if (RELU) v = fmaxf(v, 0.f);
        if (OUT_BF16) ((unsigned short*)Cp)[(size_t)row*N + col] = f2bf(v);
        else          ((float*)Cp)[(size_t)row*N + col] = v;
      }
    }
  }
}

// ---------------------------------------------------------------- V transpose
__global__ __launch_bounds__(256) void transpose_v(
    const unsigned short* __restrict__ V, unsigned short* __restrict__ Vt){
  __shared__ unsigned short t[32][33];
  int g = blockIdx.z;
  int j0 = blockIdx.x*32, e0 = blockIdx.y*32;
  int tx = threadIdx.x, ty = threadIdx.y;      // 32 x 8
  const unsigned short* Vg = V + (long)g*262144;
  unsigned short* Vtg = Vt + (long)g*262144;
  #pragma unroll
  for (int i = 0; i < 4; ++i)
    t[ty + 8*i][tx] = Vg[(long)(j0 + ty + 8*i)*128 + e0 + tx];
  __syncthreads();
  #pragma unroll
  for (int i = 0; i < 4; ++i)
    Vtg[(long)(e0 + ty + 8*i)*2048 + j0 + tx] = t[tx][ty + 8*i];
}

// ---------------------------------------------------------------- fused attention
// R10 body with ONE structural change: P stores go through a per-wave 8KB LDS
// tile, then out as COALESCED full-line writes (16 lanes x float4 = 256B
// contiguous per row, 4 rows per instruction). The old path scattered 16B
// per lane at 8KB stride -> 32B-granular L2 write transactions; R13's NT
// experiment measured 1.64x write amplification, identifying write-transaction
// throughput as attn's real wall. LDS 96KB -> 1 block/CU (2nd block was worth
// ~0 per R9).
__global__ __launch_bounds__(256) void attn_fused(
    const unsigned short* __restrict__ Q, const unsigned short* __restrict__ K,
    const unsigned short* __restrict__ Vt, float* __restrict__ P,
    unsigned short* __restrict__ CTX)
{
  __shared__ __align__(16) char lds[98304];   // K 2x16K | Vt 2x16K @32768 | P 32K @65536
  char* ldsK = lds;
  char* ldsV = lds + 32768;
  char* ldsP = lds + 65536;
  const int tid  = threadIdx.x;       // 0..255
  const int lane = tid & 63;
  const int w    = tid >> 6;          // 0..3
  const int l31  = lane & 31;
  const int hi   = lane >> 5;         // 0,1
  const float scale = 0.08838834764831845f;    // 128^-0.5

  const int d  = blockIdx.x;          // 0..511
  const int i  = d >> 3;              // 0..63
  const int g  = (d & 7) + 8*(i >> 4);
  const int q0 = (i & 15) * 128;

  const char* KbB = (const char*)(K  + (size_t)g*262144);
  const char* VtB = (const char*)(Vt + (size_t)g*262144);
  const unsigned short* Qb = Q + (size_t)g*262144 + (size_t)(q0 + w*32)*128;
  float* Pb = P + (size_t)g*4194304 + (size_t)(q0 + w*32)*2048;

  bf16x8 qf[8];
  #pragma unroll
  for (int kk = 0; kk < 8; ++kk)
    qf[kk] = *(const bf16x8*)((const char*)Qb + (size_t)l31*256 + kk*32 + hi*16);

  auto stageK = [&](int buf, int j0b){
    #pragma unroll
    for (int r = 0; r < 4; ++r){
      int o = r*4096 + tid*16;
      int j = o >> 8, c = o & 255;
      gld_lds16(KbB + (size_t)(j0b + j)*256 + (c ^ ((j & 15) << 4)),
                ldsK + buf*16384 + o);
    }
  };
  auto stageV = [&](int buf, int j0b){
    #pragma unroll
    for (int r = 0; r < 4; ++r){
      int o = r*4096 + tid*16;
      int e = o >> 7, c = o & 127;
      gld_lds16(VtB + (size_t)e*4096 + j0b*2 + (c ^ ((e & 7) << 4)),
                ldsV + buf*16384 + o);
    }
  };
  auto readK = [&](int buf, int jloc, int kk) -> bf16x8 {
    int row = jloc + l31;
    int col = (kk*32 + hi*16) ^ ((l31 & 15) << 4);
    return *(const bf16x8*)(ldsK + buf*16384 + row*256 + col);
  };
  auto readV = [&](int buf, int jloc, int c16, int t) -> bf16x8 {
    int row = t*32 + l31;
    int col = (jloc*2 + c16*32 + hi*16) ^ ((row & 7) << 4);
    return *(const bf16x8*)(ldsV + buf*16384 + row*128 + col);
  };

  // ---------------- pass 1 ----------------
  int buf = 0;
  stageK(0, 0);
  __syncthreads();
  float lacc = 0.f;
  for (int st = 0; st < 32; ++st){
    if (st < 31) stageK(buf ^ 1, (st + 1) * 64);
    #pragma unroll
    for (int jt = 0; jt < 2; ++jt){
      const int jloc = jt * 32;
      f32x16 s1 = {}, s2 = {};
      #pragma unroll
      for (int kk = 0; kk < 4; ++kk){
        s1 = __builtin_amdgcn_mfma_f32_32x32x16_bf16(readK(buf, jloc, kk),   qf[kk],   s1, 0, 0, 0);
        s2 = __builtin_amdgcn_mfma_f32_32x32x16_bf16(readK(buf, jloc, kk+4), qf[kk+4], s2, 0, 0, 0);
      }
      #pragma unroll
      for (int r = 0; r < 16; ++r) lacc += __expf((s1[r] + s2[r]) * scale);
    }
    __syncthreads();
    buf ^= 1;
  }
  lacc += __shfl_xor(lacc, 32, 64);
  const float invl = 1.f / lacc;

  // ---------------- pass 2 ----------------
  stageK(0, 0); stageV(0, 0);
  __syncthreads();
  f32x16 O[4] = {};
  buf = 0;
  for (int st = 0; st < 32; ++st){
    if (st < 31){ stageK(buf ^ 1, (st + 1) * 64); stageV(buf ^ 1, (st + 1) * 64); }
    #pragma unroll
    for (int jt = 0; jt < 2; ++jt){
      const int jloc  = jt * 32;
      f32x16 s1 = {}, s2 = {};
      #pragma unroll
      for (int kk = 0; kk < 4; ++kk){
        s1 = __builtin_amdgcn_mfma_f32_32x32x16_bf16(readK(buf, jloc, kk),   qf[kk],   s1, 0, 0, 0);
        s2 = __builtin_amdgcn_mfma_f32_32x32x16_bf16(readK(buf, jloc, kk+4), qf[kk+4], s2, 0, 0, 0);
      }
      float p[16];
      #pragma unroll
      for (int r = 0; r < 16; ++r) p[r] = __expf((s1[r] + s2[r]) * scale) * invl;
      // P tile -> per-wave LDS slice (8KB: 32 rows x 256B, XOR-swizzled).
      // p[4i..4i+3] are j-consecutive: j = jloc + 4*hi + 8*i + {0..3}.
      {
        char* pw = ldsP + w*8192 + l31*256;
        const int cbase = jloc*4 + hi*16;
        const int sw = (l31 & 15) << 4;
        f32x4 v0, v1, v2, v3;
        v0[0]=p[0];  v0[1]=p[1];  v0[2]=p[2];  v0[3]=p[3];
        v1[0]=p[4];  v1[1]=p[5];  v1[2]=p[6];  v1[3]=p[7];
        v2[0]=p[8];  v2[1]=p[9];  v2[2]=p[10]; v2[3]=p[11];
        v3[0]=p[12]; v3[1]=p[13]; v3[2]=p[14]; v3[3]=p[15];
        *(f32x4*)(pw + ((cbase      ) ^ sw)) = v0;
        *(f32x4*)(pw + ((cbase + 32) ^ sw)) = v1;
        *(f32x4*)(pw + ((cbase + 64) ^ sw)) = v2;
        *(f32x4*)(pw + ((cbase + 96) ^ sw)) = v3;
      }
      // bf16 pack + lane<->lane+32 exchange -> PV A-frags (unchanged)
      unsigned int pk[8];
      #pragma unroll
      for (int ii = 0; ii < 8; ++ii)
        pk[ii] = (unsigned int)f2bf(p[2*ii]) | ((unsigned int)f2bf(p[2*ii+1]) << 16);
      unsigned int r0 = (unsigned int)__shfl_xor((int)(hi ? pk[0] : pk[2]), 32, 64);
      unsigned int r1 = (unsigned int)__shfl_xor((int)(hi ? pk[1] : pk[3]), 32, 64);
      unsigned int r2 = (unsigned int)__shfl_xor((int)(hi ? pk[4] : pk[6]), 32, 64);
      unsigned int r3 = (unsigned int)__shfl_xor((int)(hi ? pk[5] : pk[7]), 32, 64);
      union U { unsigned int u[4]; bf16x8 v; };
      U a0, a1;
      a0.u[0] = hi ? r0    : pk[0];  a0.u[1] = hi ? r1    : pk[1];
      a0.u[2] = hi ? pk[2] : r0;     a0.u[3] = hi ? pk[3] : r1;
      a1.u[0] = hi ? r2    : pk[4];  a1.u[1] = hi ? r3    : pk[5];
      a1.u[2] = hi ? pk[6] : r2;     a1.u[3] = hi ? pk[7] : r3;
      #pragma unroll
      for (int t = 0; t < 4; ++t){
        O[t] = __builtin_amdgcn_mfma_f32_32x32x16_bf16(a0.v, readV(buf, jloc, 0, t), O[t], 0, 0, 0);
        O[t] = __builtin_amdgcn_mfma_f32_32x32x16_bf16(a1.v, readV(buf, jloc, 1, t), O[t], 0, 0, 0);
      }
    }
    // coalesced P store: wave reads back its LDS tile and writes full lines.
    // Per instruction: 4 rows x (16 lanes x 16B = 256B contiguous).
    {
      const int rsub = lane >> 4;        // 0..3
      const int c16  = lane & 15;        // 0..15
      #pragma unroll
      for (int it = 0; it < 8; ++it){
        int row = it*4 + rsub;
        int col = (c16*16) ^ ((row & 15) << 4);
        f32x4 v = *(const f32x4*)(ldsP + w*8192 + row*256 + col);
        *(f32x4*)(Pb + (size_t)row*2048 + st*64 + c16*4) = v;
      }
    }
    __syncthreads();
    buf ^= 1;
  }

  #pragma unroll
  for (int t = 0; t < 4; ++t){
    #pragma unroll
    for (int r = 0; r < 16; ++r){
      int qrow = (r & 3) + 8*(r >> 2) + 4*hi;
      CTX[(size_t)g*262144 + (size_t)(q0 + w*32 + qrow)*128 + t*32 + l31] = f2bf(O[t][r]);
    }
  }
}

// ---------------------------------------------------------------- LayerNorm
DEV float block_sum256(float v, float* red){
  #pragma unroll
  for (int off = 32; off > 0; off >>= 1) v += __shfl_xor(v, off, 64);
  int lane = threadIdx.x & 63, wid = threadIdx.x >> 6;
  if (lane == 0) red[wid] = v;
  __syncthreads();
  return (red[0]+red[1]) + (red[2]+red[3]);
}

template<bool WRITE_F32, bool WRITE_BF>
__global__ __launch_bounds__(256) void ln_residual_bf(
    const unsigned short* __restrict__ A, const unsigned short* __restrict__ R,
    const float* __restrict__ gamma, const float* __restrict__ beta,
    float* __restrict__ outf, unsigned short* __restrict__ outb){
  __shared__ float red1[4], red2[4];
  long base = (long)blockIdx.x * 1024;
  int tid = threadIdx.x;
  ushort4 a = *(const ushort4*)(A + base + tid*4);
  ushort4 r = *(const ushort4*)(R + base + tid*4);
  float v[4] = { bf2f(a.x)+bf2f(r.x), bf2f(a.y)+bf2f(r.y),
                 bf2f(a.z)+bf2f(r.z), bf2f(a.w)+bf2f(r.w) };
  float s = (v[0]+v[1]) + (v[2]+v[3]);
  s = block_sum256(s, red1);
  float mean = s * (1.f/1024.f);
  float dd[4] = {v[0]-mean, v[1]-mean, v[2]-mean, v[3]-mean};
  float sq = (dd[0]*dd[0]+dd[1]*dd[1]) + (dd[2]*dd[2]+dd[3]*dd[3]);
  sq = block_sum256(sq, red2);
  float rstd = rsqrtf(sq*(1.f/1024.f) + 1e-5f);
  float4 g4 = *(const float4*)(gamma + tid*4);
  float4 b4 = *(const float4*)(beta  + tid*4);
  float o[4] = { dd[0]*rstd*g4.x + b4.x, dd[1]*rstd*g4.y + b4.y,
                 dd[2]*rstd*g4.z + b4.z, dd[3]*rstd*g4.w + b4.w };
  if (WRITE_F32){
    float4 o4; o4.x=o[0]; o4.y=o[1]; o4.z=o[2]; o4.w=o[3];
    *(float4*)(outf + base + tid*4) = o4;
  }
  if (WRITE_BF){
    ushort4 ob; ob.x=f2bf(o[0]); ob.y=f2bf(o[1]); ob.z=f2bf(o[2]); ob.w=f2bf(o[3]);
    *(ushort4*)(outb + base + tid*4) = ob;
  }
}

// ---------------------------------------------------------------- host
extern "C" void kernel_launch(void* const* d_in, const int* in_sizes, int n_in,
                              void* d_out, int out_size, void* d_ws, size_t ws_size,
                              hipStream_t stream){
  const float* X   = (const float*)d_in[0];
  const float* Wq  = (const float*)d_in[1];
  const float* bq  = (const float*)d_in[2];
  const float* Wk  = (const float*)d_in[3];
  const float* bk  = (const float*)d_in[4];
  const float* Wv  = (const float*)d_in[5];
  const float* bv  = (const float*)d_in[6];
  const float* Wo  = (const float*)d_in[7];
  const float* bo  = (const float*)d_in[8];
  const float* g1  = (const float*)d_in[9];
  const float* b1n = (const float*)d_in[10];
  const float* W1  = (const float*)d_in[11];
  const float* b1  = (const float*)d_in[12];
  const float* W2  = (const float*)d_in[13];
  const float* b2  = (const float*)d_in[14];
  const float* g2  = (const float*)d_in[15];
  const float* b2n = (const float*)d_in[16];

  const int M = 8192, D = 1024, F = 2048;
  const long YSZ = (long)M * D;
  float* y_out = (float*)d_out;
  float* atten = (float*)d_out + YSZ;        // 32 x 2048 x 2048 fp32

  char* w = (char*)d_ws;
  auto alloc = [&](size_t bytes){ char* p = w; w += (bytes + 255) & ~(size_t)255; return p; };
  unsigned short* Xbf   = (unsigned short*)alloc((size_t)M*D*2);
  unsigned short* Wqbf  = (unsigned short*)alloc((size_t)D*D*2);
  unsigned short* Wkbf  = (unsigned short*)alloc((size_t)D*D*2);
  unsigned short* Wvbf  = (unsigned short*)alloc((size_t)D*D*2);
  unsigned short* Wobf  = (unsigned short*)alloc((size_t)D*D*2);
  unsigned short* W1bf  = (unsigned short*)alloc((size_t)F*D*2);
  unsigned short* W2bf  = (unsigned short*)alloc((size_t)D*F*2);
  unsigned short* Qbf   = (unsigned short*)alloc((size_t)M*D*2);
  unsigned short* Kbf   = (unsigned short*)alloc((size_t)M*D*2);
  unsigned short* Vbf   = (unsigned short*)alloc((size_t)M*D*2);
  unsigned short* Vtbf  = (unsigned short*)alloc((size_t)M*D*2);
  unsigned short* CTXbf = (unsigned short*)alloc((size_t)M*D*2);
  unsigned short* Hbf   = (unsigned short*)alloc((size_t)M*D*2);
  unsigned short* F1bf  = (unsigned short*)alloc((size_t)M*F*2);
  unsigned short* TMPbf = (unsigned short*)alloc((size_t)M*D*2);

  auto cvt = [&](const float* src, unsigned short* dst, int n){
    int blocks = (n/4 + 255)/256; if (blocks > 4096) blocks = 4096;
    cvt_f32_bf16<<<blocks, 256, 0, stream>>>(src, dst, n);
  };
  cvt(X,  Xbf,  M*D);
  cvt(Wq, Wqbf, D*D);  cvt(Wk, Wkbf, D*D);  cvt(Wv, Wvbf, D*D);  cvt(Wo, Wobf, D*D);
  cvt(W1, W1bf, F*D);  cvt(W2, W2bf, D*F);

  dim3 blk2(512);

  // Q/K/V projections: [8192,1024] = X @ W^T + b  -> bf16
  gemm_bt2<true,false,true><<<dim3((M/256)*(D/128)), blk2, 0, stream>>>(Xbf, Wqbf, bq, Qbf, D, D);
  gemm_bt2<true,false,true><<<dim3((M/256)*(D/128)), blk2, 0, stream>>>(Xbf, Wkbf, bk, Kbf, D, D);
  gemm_bt2<true,false,true><<<dim3((M/256)*(D/128)), blk2, 0, stream>>>(Xbf, Wvbf, bv, Vbf, D, D);

  // V -> Vt per group (e-major rows for PV B-operand staging)
  transpose_v<<<dim3(64, 4, 32), dim3(32, 8), 0, stream>>>(Vbf, Vtbf);

  // fused attention (R10 body + LDS-coalesced P stores)
  attn_fused<<<dim3(512), dim3(256), 0, stream>>>(Qbf, Kbf, Vtbf, atten, CTXbf);

  // out = ctx @ Wo^T + bo -> TMPbf (bf16)
  gemm_bt2<true,false,true><<<dim3((M/256)*(D/128)), blk2, 0, stream>>>(CTXbf, Wobf, bo, TMPbf, D, D);

  // h = LN1(X + out) -> Hbf (bf16 only)
  ln_residual_bf<false,true><<<M, 256, 0, stream>>>(Xbf, TMPbf, g1, b1n, nullptr, Hbf);

  // f1 = relu(h @ W1^T + b1) -> bf16
  gemm_bt2<true,true,true><<<dim3((M/256)*(F/128)), blk2, 0, stream>>>(Hbf, W1bf, b1, F1bf, F, D);

  // f = f1 @ W2^T + b2 -> TMPbf (bf16)
  gemm_bt2<true,false,true><<<dim3((M/256)*(D/128)), blk2, 0, stream>>>(F1bf, W2bf, b2, TMPbf, D, F);

  // y = LN2(h + f) -> d_out
  ln_residual_bf<true,false><<<M, 256, 0, stream>>>(Hbf, TMPbf, g2, b2n, y_out, nullptr);
}

// Round 15
// 439.885 us; speedup vs baseline: 1.6309x; 1.0905x over previous
//
#include <hip/hip_runtime.h>
#include <stdint.h>

using f32x4  = __attribute__((ext_vector_type(4))) float;
using f32x16 = __attribute__((ext_vector_type(16))) float;
using bf16x8 = __attribute__((ext_vector_type(8))) short;

#define DEV static __device__ __forceinline__

DEV unsigned short f2bf(float f){
  union { float f; unsigned int u; } c; c.f = f;
  unsigned int u = c.u;
  u += 0x7FFFu + ((u >> 16) & 1u);   // round-to-nearest-even
  return (unsigned short)(u >> 16);
}
DEV float bf2f(unsigned short u){
  union { unsigned int u; float f; } c; c.u = ((unsigned int)u) << 16; return c.f;
}

DEV void gld_lds16(const void* g, void* l){
  __builtin_amdgcn_global_load_lds(
      (const __attribute__((address_space(1))) void*)g,
      (__attribute__((address_space(3))) void*)l, 16, 0, 0);
}

// ---------------------------------------------------------------- converts
// one launch, 7 segments (X + 6 weights); dests contiguous in ws
struct CvtArgs { const float* src[7]; int cum[8]; };
__global__ __launch_bounds__(256) void cvt_multi(CvtArgs a, unsigned short* __restrict__ dst){
  const int total = a.cum[7];
  for (int i = (blockIdx.x*256 + threadIdx.x)*4; i < total; i += gridDim.x*1024){
    int s = 0;
    #pragma unroll
    for (int k = 1; k < 7; ++k) s += (i >= a.cum[k]);
    const float* src = a.src[s];
    const int off = i - a.cum[s];
    float4 v = *(const float4*)(src + off);
    ushort4 o; o.x=f2bf(v.x); o.y=f2bf(v.y); o.z=f2bf(v.z); o.w=f2bf(v.w);
    *(ushort4*)(dst + i) = o;
  }
}

// ---------------------------------------------------------------- GEMM v2
// (byte-identical to round 10 — proven winner, untouched)
template<bool OUT_BF16, bool RELU, bool HAS_BIAS>
__global__ __launch_bounds__(512, 2)
void gemm_bt2(const unsigned short* __restrict__ Ap, const unsigned short* __restrict__ Bp,
              const float* __restrict__ bias, void* __restrict__ Cp, int N, int K)
{
  __shared__ __align__(16) char lds[131072];  // A: 3x32K @0 | B: 2x16K @98304
  const int tid  = threadIdx.x;
  const int lane = tid & 63;
  const int wid  = tid >> 6;          // 0..7
  const int wm   = wid >> 2;          // 0,1
  const int wn   = wid & 3;           // 0..3
  const int mrow = lane & 15;
  const int krow = lane >> 4;

  const int nbx = N >> 7;
  const int nwg = gridDim.x;
  const int d   = blockIdx.x;
  const int swz = (d & 7)*(nwg >> 3) + (d >> 3);
  const int bx  = swz % nbx, by = swz / nbx;

  const size_t Kb = (size_t)K * 2;
  const char* Ab = (const char*)(Ap + (size_t)by*256*K);
  const char* Bb = (const char*)(Bp + (size_t)bx*128*K);
  const int NT = K >> 6;

  auto stageA = [&](int t){
    char* dst = lds + (t % 3)*32768;
    const char* src = Ab + (size_t)t*128;
    #pragma unroll
    for (int s = 0; s < 4; ++s){
      int o = s*8192 + tid*16;
      int row = o >> 7, cb = o & 127;
      gld_lds16(src + (size_t)row*Kb + (cb ^ ((row & 7) << 4)), dst + o);
    }
  };
  auto stageB = [&](int t){
    char* dst = lds + 98304 + (t & 1)*16384;
    const char* src = Bb + (size_t)t*128;
    #pragma unroll
    for (int s = 0; s < 2; ++s){
      int o = s*8192 + tid*16;
      int row = o >> 7, cb = o & 127;
      gld_lds16(src + (size_t)row*Kb + (cb ^ ((row & 7) << 4)), dst + o);
    }
  };

  f32x4 acc[8][2] = {};

  stageA(0); stageB(0); stageA(1);
  asm volatile("s_waitcnt vmcnt(4)" ::: "memory");
  __builtin_amdgcn_s_barrier();

  for (int t = 0; t < NT; ++t){
    if (t + 1 < NT) stageB(t + 1);
    if (t + 2 < NT) stageA(t + 2);

    const char* baseA = lds + (t % 3)*32768;
    const char* baseB = lds + 98304 + (t & 1)*16384;

    bf16x8 b[2][2];
    #pragma unroll
    for (int ni = 0; ni < 2; ++ni){
      int row = wn*32 + ni*16 + mrow;
      #pragma unroll
      for (int ks = 0; ks < 2; ++ks)
        b[ni][ks] = *(const bf16x8*)(baseB + row*128 + ((ks*64 + krow*16) ^ ((row & 7) << 4)));
    }
    bf16x8 a[8][2];
    #pragma unroll
    for (int mi = 0; mi < 8; ++mi){
      int row = wm*128 + mi*16 + mrow;
      #pragma unroll
      for (int ks = 0; ks < 2; ++ks)
        a[mi][ks] = *(const bf16x8*)(baseA + row*128 + ((ks*64 + krow*16) ^ ((row & 7) << 4)));
    }

    __builtin_amdgcn_s_setprio(1);
    #pragma unroll
    for (int ks = 0; ks < 2; ++ks)
      #pragma unroll
      for (int mi = 0; mi < 8; ++mi)
        #pragma unroll
        for (int ni = 0; ni < 2; ++ni)
          acc[mi][ni] = __builtin_amdgcn_mfma_f32_16x16x32_bf16(a[mi][ks], b[ni][ks], acc[mi][ni], 0, 0, 0);
    __builtin_amdgcn_s_setprio(0);

    if (t + 1 < NT){
      if (t + 2 < NT) asm volatile("s_waitcnt vmcnt(4)" ::: "memory");
      else            asm volatile("s_waitcnt vmcnt(0)" ::: "memory");
      __builtin_amdgcn_s_barrier();
      __builtin_amdgcn_sched_barrier(0);
    }
  }

  int row0 = by*256 + wm*128;
  int col0 = bx*128 + wn*32;
  #pragma unroll
  for (int mi = 0; mi < 8; ++mi){
    #pragma unroll
    for (int ni = 0; ni < 2; ++ni){
      int col = col0 + ni*16 + mrow;
      float bv = HAS_BIAS ? bias[col] : 0.f;
      #pragma unroll
      for (int r = 0; r < 4; ++r){
        int row = row0 + mi*16 + krow*4 + r;
        float v = acc[mi][ni][r] + bv;
        if (RELU) v = fmaxf(v, 0.f);
        if (OUT_BF16) ((unsigned short*)Cp)[(size_t)row*N + col] = f2bf(v);
        else          ((float*)Cp)[(size_t)row*N + col] = v;
      }
    }
  }
}

// ---------------------------------------------------------------- fused QKV GEMM
// Same pipeline as gemm_bt2, N=3072 (B = concat Wq|Wk|Wv, contiguous in ws),
// K=1024. Epilogue routes by which = col>>10 (uniform per block):
//   which 0 -> Q[row*1024+cq], which 1 -> K[...], which 2 -> Vt direct
//   (4 consecutive acc rows = 4 consecutive j -> contiguous ushort4 in Vt).
__global__ __launch_bounds__(512, 2)
void gemm_qkv(const unsigned short* __restrict__ Ap, const unsigned short* __restrict__ Bp,
              const float* __restrict__ bq, const float* __restrict__ bk,
              const float* __restrict__ bv,
              unsigned short* __restrict__ Qo, unsigned short* __restrict__ Ko,
              unsigned short* __restrict__ Vto)
{
  constexpr int N = 3072, K = 1024;
  __shared__ __align__(16) char lds[131072];
  const int tid  = threadIdx.x;
  const int lane = tid & 63;
  const int wid  = tid >> 6;
  const int wm   = wid >> 2;
  const int wn   = wid & 3;
  const int mrow = lane & 15;
  const int krow = lane >> 4;

  const int nbx = N >> 7;             // 24
  const int nwg = gridDim.x;          // 768
  const int d   = blockIdx.x;
  const int swz = (d & 7)*(nwg >> 3) + (d >> 3);
  const int bx  = swz % nbx, by = swz / nbx;

  const size_t Kb = (size_t)K * 2;
  const char* Ab = (const char*)(Ap + (size_t)by*256*K);
  const char* Bb = (const char*)(Bp + (size_t)bx*128*K);
  const int NT = K >> 6;              // 16

  auto stageA = [&](int t){
    char* dst = lds + (t % 3)*32768;
    const char* src = Ab + (size_t)t*128;
    #pragma unroll
    for (int s = 0; s < 4; ++s){
      int o = s*8192 + tid*16;
      int row = o >> 7, cb = o & 127;
      gld_lds16(src + (size_t)row*Kb + (cb ^ ((row & 7) << 4)), dst + o);
    }
  };
  auto stageB = [&](int t){
    char* dst = lds + 98304 + (t & 1)*16384;
    const char* src = Bb + (size_t)t*128;
    #pragma unroll
    for (int s = 0; s < 2; ++s){
      int o = s*8192 + tid*16;
      int row = o >> 7, cb = o & 127;
      gld_lds16(src + (size_t)row*Kb + (cb ^ ((row & 7) << 4)), dst + o);
    }
  };

  f32x4 acc[8][2] = {};

  stageA(0); stageB(0); stageA(1);
  asm volatile("s_waitcnt vmcnt(4)" ::: "memory");
  __builtin_amdgcn_s_barrier();

  for (int t = 0; t < NT; ++t){
    if (t + 1 < NT) stageB(t + 1);
    if (t + 2 < NT) stageA(t + 2);

    const char* baseA = lds + (t % 3)*32768;
    const char* baseB = lds + 98304 + (t & 1)*16384;

    bf16x8 b[2][2];
    #pragma unroll
    for (int ni = 0; ni < 2; ++ni){
      int row = wn*32 + ni*16 + mrow;
      #pragma unroll
      for (int ks = 0; ks < 2; ++ks)
        b[ni][ks] = *(const bf16x8*)(baseB + row*128 + ((ks*64 + krow*16) ^ ((row & 7) << 4)));
    }
    bf16x8 a[8][2];
    #pragma unroll
    for (int mi = 0; mi < 8; ++mi){
      int row = wm*128 + mi*16 + mrow;
      #pragma unroll
      for (int ks = 0; ks < 2; ++ks)
        a[mi][ks] = *(const bf16x8*)(baseA + row*128 + ((ks*64 + krow*16) ^ ((row & 7) << 4)));
    }

    __builtin_amdgcn_s_setprio(1);
    #pragma unroll
    for (int ks = 0; ks < 2; ++ks)
      #pragma unroll
      for (int mi = 0; mi < 8; ++mi)
        #pragma unroll
        for (int ni = 0; ni < 2; ++ni)
          acc[mi][ni] = __builtin_amdgcn_mfma_f32_16x16x32_bf16(a[mi][ks], b[ni][ks], acc[mi][ni], 0, 0, 0);
    __builtin_amdgcn_s_setprio(0);

    if (t + 1 < NT){
      if (t + 2 < NT) asm volatile("s_waitcnt vmcnt(4)" ::: "memory");
      else            asm volatile("s_waitcnt vmcnt(0)" ::: "memory");
      __builtin_amdgcn_s_barrier();
      __builtin_amdgcn_sched_barrier(0);
    }
  }

  const int row0  = by*256 + wm*128;
  const int col0g = bx*128 + wn*32;        // global col in [0,3072)
  const int which = col0g >> 10;           // uniform per block (1024%128==0)
  const float* bias = which == 0 ? bq : (which == 1 ? bk : bv);
  unsigned short* out01 = which == 0 ? Qo : Ko;

  if (which < 2){
    #pragma unroll
    for (int mi = 0; mi < 8; ++mi){
      #pragma unroll
      for (int ni = 0; ni < 2; ++ni){
        int cq = (col0g & 1023) + ni*16 + mrow;
        float bvv = bias[cq];
        #pragma unroll
        for (int r = 0; r < 4; ++r){
          int row = row0 + mi*16 + krow*4 + r;
          out01[(size_t)row*1024 + cq] = f2bf(acc[mi][ni][r] + bvv);
        }
      }
    }
  } else {
    // V -> Vt[g][e][j]: e = cq, j = row&2047; 4 consecutive r = ushort4
    #pragma unroll
    for (int mi = 0; mi < 8; ++mi){
      #pragma unroll
      for (int ni = 0; ni < 2; ++ni){
        int cq = (col0g & 1023) + ni*16 + mrow;
        float bvv = bias[cq];
        int rowb = row0 + mi*16 + krow*4;
        int gg = rowb >> 11;
        int j  = rowb & 2047;
        ushort4 o;
        o.x = f2bf(acc[mi][ni][0] + bvv);
        o.y = f2bf(acc[mi][ni][1] + bvv);
        o.z = f2bf(acc[mi][ni][2] + bvv);
        o.w = f2bf(acc[mi][ni][3] + bvv);
        *(ushort4*)(Vto + (size_t)gg*262144 + (size_t)cq*2048 + j) = o;
      }
    }
  }
}

// ---------------------------------------------------------------- fused attention
// (byte-identical to round 10 — the proven ~228us body)
__global__ __launch_bounds__(256, 2) void attn_fused(
    const unsigned short* __restrict__ Q, const unsigned short* __restrict__ K,
    const unsigned short* __restrict__ Vt, float* __restrict__ P,
    unsigned short* __restrict__ CTX)
{
  __shared__ __align__(16) char lds[65536];   // K dbuf 2x16K | Vt dbuf 2x16K
  char* ldsK = lds;
  char* ldsV = lds + 32768;
  const int tid  = threadIdx.x;       // 0..255
  const int lane = tid & 63;
  const int w    = tid >> 6;          // 0..3
  const int l31  = lane & 31;
  const int hi   = lane >> 5;         // 0,1
  const float scale = 0.08838834764831845f;    // 128^-0.5

  const int d  = blockIdx.x;          // 0..511
  const int i  = d >> 3;              // 0..63
  const int g  = (d & 7) + 8*(i >> 4);
  const int q0 = (i & 15) * 128;

  const char* KbB = (const char*)(K  + (size_t)g*262144);
  const char* VtB = (const char*)(Vt + (size_t)g*262144);
  const unsigned short* Qb = Q + (size_t)g*262144 + (size_t)(q0 + w*32)*128;
  float* Pb = P + (size_t)g*4194304 + (size_t)(q0 + w*32)*2048;

  bf16x8 qf[8];
  #pragma unroll
  for (int kk = 0; kk < 8; ++kk)
    qf[kk] = *(const bf16x8*)((const char*)Qb + (size_t)l31*256 + kk*32 + hi*16);

  auto stageK = [&](int buf, int j0b){
    #pragma unroll
    for (int r = 0; r < 4; ++r){
      int o = r*4096 + tid*16;
      int j = o >> 8, c = o & 255;
      gld_lds16(KbB + (size_t)(j0b + j)*256 + (c ^ ((j & 15) << 4)),
                ldsK + buf*16384 + o);
    }
  };
  auto stageV = [&](int buf, int j0b){
    #pragma unroll
    for (int r = 0; r < 4; ++r){
      int o = r*4096 + tid*16;
      int e = o >> 7, c = o & 127;
      gld_lds16(VtB + (size_t)e*4096 + j0b*2 + (c ^ ((e & 7) << 4)),
                ldsV + buf*16384 + o);
    }
  };
  auto readK = [&](int buf, int jloc, int kk) -> bf16x8 {
    int row = jloc + l31;
    int col = (kk*32 + hi*16) ^ ((l31 & 15) << 4);
    return *(const bf16x8*)(ldsK + buf*16384 + row*256 + col);
  };
  auto readV = [&](int buf, int jloc, int c16, int t) -> bf16x8 {
    int row = t*32 + l31;
    int col = (jloc*2 + c16*32 + hi*16) ^ ((row & 7) << 4);
    return *(const bf16x8*)(ldsV + buf*16384 + row*128 + col);
  };

  // ---------------- pass 1 ----------------
  int buf = 0;
  stageK(0, 0);
  __syncthreads();
  float lacc = 0.f;
  for (int st = 0; st < 32; ++st){
    if (st < 31) stageK(buf ^ 1, (st + 1) * 64);
    #pragma unroll
    for (int jt = 0; jt < 2; ++jt){
      const int jloc = jt * 32;
      f32x16 s1 = {}, s2 = {};
      #pragma unroll
      for (int kk = 0; kk < 4; ++kk){
        s1 = __builtin_amdgcn_mfma_f32_32x32x16_bf16(readK(buf, jloc, kk),   qf[kk],   s1, 0, 0, 0);
        s2 = __builtin_amdgcn_mfma_f32_32x32x16_bf16(readK(buf, jloc, kk+4), qf[kk+4], s2, 0, 0, 0);
      }
      #pragma unroll
      for (int r = 0; r < 16; ++r) lacc += __expf((s1[r] + s2[r]) * scale);
    }
    __syncthreads();
    buf ^= 1;
  }
  lacc += __shfl_xor(lacc, 32, 64);
  const float invl = 1.f / lacc;

  // ---------------- pass 2 ----------------
  stageK(0, 0); stageV(0, 0);
  __syncthreads();
  f32x16 O[4] = {};
  buf = 0;
  for (int st = 0; st < 32; ++st){
    if (st < 31){ stageK(buf ^ 1, (st + 1) * 64); stageV(buf ^ 1, (st + 1) * 64); }
    #pragma unroll
    for (int jt = 0; jt < 2; ++jt){
      const int jloc  = jt * 32;
      const int jglob = st*64 + jloc;
      f32x16 s1 = {}, s2 = {};
      #pragma unroll
      for (int kk = 0; kk < 4; ++kk){
        s1 = __builtin_amdgcn_mfma_f32_32x32x16_bf16(readK(buf, jloc, kk),   qf[kk],   s1, 0, 0, 0);
        s2 = __builtin_amdgcn_mfma_f32_32x32x16_bf16(readK(buf, jloc, kk+4), qf[kk+4], s2, 0, 0, 0);
      }
      float p[16];
      #pragma unroll
      for (int r = 0; r < 16; ++r) p[r] = __expf((s1[r] + s2[r]) * scale) * invl;
      float* prow = Pb + (size_t)l31*2048 + jglob + hi*4;
      *(float4*)(prow)      = make_float4(p[0],  p[1],  p[2],  p[3]);
      *(float4*)(prow + 8)  = make_float4(p[4],  p[5],  p[6],  p[7]);
      *(float4*)(prow + 16) = make_float4(p[8],  p[9],  p[10], p[11]);
      *(float4*)(prow + 24) = make_float4(p[12], p[13], p[14], p[15]);
      unsigned int pk[8];
      #pragma unroll
      for (int ii = 0; ii < 8; ++ii)
        pk[ii] = (unsigned int)f2bf(p[2*ii]) | ((unsigned int)f2bf(p[2*ii+1]) << 16);
      unsigned int r0 = (unsigned int)__shfl_xor((int)(hi ? pk[0] : pk[2]), 32, 64);
      unsigned int r1 = (unsigned int)__shfl_xor((int)(hi ? pk[1] : pk[3]), 32, 64);
      unsigned int r2 = (unsigned int)__shfl_xor((int)(hi ? pk[4] : pk[6]), 32, 64);
      unsigned int r3 = (unsigned int)__shfl_xor((int)(hi ? pk[5] : pk[7]), 32, 64);
      union U { unsigned int u[4]; bf16x8 v; };
      U a0, a1;
      a0.u[0] = hi ? r0    : pk[0];  a0.u[1] = hi ? r1    : pk[1];
      a0.u[2] = hi ? pk[2] : r0;     a0.u[3] = hi ? pk[3] : r1;
      a1.u[0] = hi ? r2    : pk[4];  a1.u[1] = hi ? r3    : pk[5];
      a1.u[2] = hi ? pk[6] : r2;     a1.u[3] = hi ? pk[7] : r3;
      #pragma unroll
      for (int t = 0; t < 4; ++t){
        O[t] = __builtin_amdgcn_mfma_f32_32x32x16_bf16(a0.v, readV(buf, jloc, 0, t), O[t], 0, 0, 0);
        O[t] = __builtin_amdgcn_mfma_f32_32x32x16_bf16(a1.v, readV(buf, jloc, 1, t), O[t], 0, 0, 0);
      }
    }
    __syncthreads();
    buf ^= 1;
  }

  #pragma unroll
  for (int t = 0; t < 4; ++t){
    #pragma unroll
    for (int r = 0; r < 16; ++r){
      int qrow = (r & 3) + 8*(r >> 2) + 4*hi;
      CTX[(size_t)g*262144 + (size_t)(q0 + w*32 + qrow)*128 + t*32 + l31] = f2bf(O[t][r]);
    }
  }
}

// ---------------------------------------------------------------- LayerNorm
DEV float block_sum256(float v, float* red){
  #pragma unroll
  for (int off = 32; off > 0; off >>= 1) v += __shfl_xor(v, off, 64);
  int lane = threadIdx.x & 63, wid = threadIdx.x >> 6;
  if (lane == 0) red[wid] = v;
  __syncthreads();
  return (red[0]+red[1]) + (red[2]+red[3]);
}

template<bool WRITE_F32, bool WRITE_BF>
__global__ __launch_bounds__(256) void ln_residual_bf(
    const unsigned short* __restrict__ A, const unsigned short* __restrict__ R,
    const float* __restrict__ gamma, const float* __restrict__ beta,
    float* __restrict__ outf, unsigned short* __restrict__ outb){
  __shared__ float red1[4], red2[4];
  long base = (long)blockIdx.x * 1024;
  int tid = threadIdx.x;
  ushort4 a = *(const ushort4*)(A + base + tid*4);
  ushort4 r = *(const ushort4*)(R + base + tid*4);
  float v[4] = { bf2f(a.x)+bf2f(r.x), bf2f(a.y)+bf2f(r.y),
                 bf2f(a.z)+bf2f(r.z), bf2f(a.w)+bf2f(r.w) };
  float s = (v[0]+v[1]) + (v[2]+v[3]);
  s = block_sum256(s, red1);
  float mean = s * (1.f/1024.f);
  float dd[4] = {v[0]-mean, v[1]-mean, v[2]-mean, v[3]-mean};
  float sq = (dd[0]*dd[0]+dd[1]*dd[1]) + (dd[2]*dd[2]+dd[3]*dd[3]);
  sq = block_sum256(sq, red2);
  float rstd = rsqrtf(sq*(1.f/1024.f) + 1e-5f);
  float4 g4 = *(const float4*)(gamma + tid*4);
  float4 b4 = *(const float4*)(beta  + tid*4);
  float o[4] = { dd[0]*rstd*g4.x + b4.x, dd[1]*rstd*g4.y + b4.y,
                 dd[2]*rstd*g4.z + b4.z, dd[3]*rstd*g4.w + b4.w };
  if (WRITE_F32){
    float4 o4; o4.x=o[0]; o4.y=o[1]; o4.z=o[2]; o4.w=o[3];
    *(float4*)(outf + base + tid*4) = o4;
  }
  if (WRITE_BF){
    ushort4 ob; ob.x=f2bf(o[0]); ob.y=f2bf(o[1]); ob.z=f2bf(o[2]); ob.w=f2bf(o[3]);
    *(ushort4*)(outb + base + tid*4) = ob;
  }
}

// ---------------------------------------------------------------- host
extern "C" void kernel_launch(void* const* d_in, const int* in_sizes, int n_in,
                              void* d_out, int out_size, void* d_ws, size_t ws_size,
                              hipStream_t stream){
  const float* X   = (const float*)d_in[0];
  const float* Wq  = (const float*)d_in[1];
  const float* bq  = (const float*)d_in[2];
  const float* Wk  = (const float*)d_in[3];
  const float* bk  = (const float*)d_in[4];
  const float* Wv  = (const float*)d_in[5];
  const float* bv  = (const float*)d_in[6];
  const float* Wo  = (const float*)d_in[7];
  const float* bo  = (const float*)d_in[8];
  const float* g1  = (const float*)d_in[9];
  const float* b1n = (const float*)d_in[10];
  const float* W1  = (const float*)d_in[11];
  const float* b1  = (const float*)d_in[12];
  const float* W2  = (const float*)d_in[13];
  const float* b2  = (const float*)d_in[14];
  const float* g2  = (const float*)d_in[15];
  const float* b2n = (const float*)d_in[16];

  const int M = 8192, D = 1024, F = 2048;
  const long YSZ = (long)M * D;
  float* y_out = (float*)d_out;
  float* atten = (float*)d_out + YSZ;        // 32 x 2048 x 2048 fp32

  char* w = (char*)d_ws;
  auto alloc = [&](size_t bytes){ char* p = w; w += (bytes + 255) & ~(size_t)255; return p; };
  // NOTE: Xbf..W2bf must stay contiguous (cvt_multi writes them as one range;
  // Wq|Wk|Wv contiguity also gives the fused QKV B matrix). Sizes are all
  // multiples of 256B so alloc() inserts no padding.
  unsigned short* Xbf   = (unsigned short*)alloc((size_t)M*D*2);
  unsigned short* Wqbf  = (unsigned short*)alloc((size_t)D*D*2);
  unsigned short* Wkbf  = (unsigned short*)alloc((size_t)D*D*2);
  unsigned short* Wvbf  = (unsigned short*)alloc((size_t)D*D*2);
  unsigned short* Wobf  = (unsigned short*)alloc((size_t)D*D*2);
  unsigned short* W1bf  = (unsigned short*)alloc((size_t)F*D*2);
  unsigned short* W2bf  = (unsigned short*)alloc((size_t)D*F*2);
  unsigned short* Qbf   = (unsigned short*)alloc((size_t)M*D*2);
  unsigned short* Kbf   = (unsigned short*)alloc((size_t)M*D*2);
  unsigned short* Vtbf  = (unsigned short*)alloc((size_t)M*D*2);
  unsigned short* CTXbf = (unsigned short*)alloc((size_t)M*D*2);
  unsigned short* Hbf   = (unsigned short*)alloc((size_t)M*D*2);
  unsigned short* F1bf  = (unsigned short*)alloc((size_t)M*F*2);
  unsigned short* TMPbf = (unsigned short*)alloc((size_t)M*D*2);
  (void)Wqbf; (void)Wkbf; (void)Wvbf;

  // single conversion launch: X + 6 weights (dests contiguous from Xbf)
  {
    CvtArgs a;
    a.src[0]=X; a.src[1]=Wq; a.src[2]=Wk; a.src[3]=Wv; a.src[4]=Wo; a.src[5]=W1; a.src[6]=W2;
    int MD = M*D, DD = D*D, FD = F*D;
    a.cum[0]=0;
    a.cum[1]=a.cum[0]+MD;  a.cum[2]=a.cum[1]+DD;  a.cum[3]=a.cum[2]+DD;
    a.cum[4]=a.cum[3]+DD;  a.cum[5]=a.cum[4]+DD;  a.cum[6]=a.cum[5]+FD;
    a.cum[7]=a.cum[6]+FD;
    cvt_multi<<<2048, 256, 0, stream>>>(a, Xbf);
  }

  dim3 blk2(512);

  // fused QKV: [8192,3072] = X @ [Wq|Wk|Wv]^T + b; V written as Vt directly
  gemm_qkv<<<dim3((M/256)*(3072/128)), blk2, 0, stream>>>(Xbf, Wqbf, bq, bk, bv, Qbf, Kbf, Vtbf);

  // fused attention (R10 proven body); 2 blocks/CU
  attn_fused<<<dim3(512), dim3(256), 0, stream>>>(Qbf, Kbf, Vtbf, atten, CTXbf);

  // out = ctx @ Wo^T + bo -> TMPbf (bf16)
  gemm_bt2<true,false,true><<<dim3((M/256)*(D/128)), blk2, 0, stream>>>(CTXbf, Wobf, bo, TMPbf, D, D);

  // h = LN1(X + out) -> Hbf (bf16 only)
  ln_residual_bf<false,true><<<M, 256, 0, stream>>>(Xbf, TMPbf, g1, b1n, nullptr, Hbf);

  // f1 = relu(h @ W1^T + b1) -> bf16
  gemm_bt2<true,true,true><<<dim3((M/256)*(F/128)), blk2, 0, stream>>>(Hbf, W1bf, b1, F1bf, F, D);

  // f = f1 @ W2^T + b2 -> TMPbf (bf16)
  gemm_bt2<true,false,true><<<dim3((M/256)*(D/128)), blk2, 0, stream>>>(F1bf, W2bf, b2, TMPbf, D, F);

  // y = LN2(h + f) -> d_out
  ln_residual_bf<true,false><<<M, 256, 0, stream>>>(Hbf, TMPbf, g2, b2n, y_out, nullptr);
}